// Round 1
// baseline (708.945 us; speedup 1.0000x reference)
//
#include <hip/hip_runtime.h>

#define N_NODES 51200
#define N_EDGES 819200
#define HDIM 128
#define NGRAPH 128
#define SEG 400
#define NOUT 10

// ---------------- CSR build ----------------

__global__ void k_count(const int* __restrict__ dst, int* __restrict__ counts) {
    int e = blockIdx.x * blockDim.x + threadIdx.x;
    if (e < N_EDGES) atomicAdd(&counts[dst[e]], 1);
}

// block = 256 threads, 4 items/thread -> 1024 elements/block; grid = 50
__global__ void k_scan_block(const int* __restrict__ counts,
                             int* __restrict__ partial,
                             int* __restrict__ blocksums) {
    __shared__ int tsum[256];
    int tid = threadIdx.x;
    int base = blockIdx.x * 1024 + tid * 4;
    int4 c = *(const int4*)(counts + base);
    int s1 = c.x, s2 = s1 + c.y, s3 = s2 + c.z, s4 = s3 + c.w;
    tsum[tid] = s4;
    __syncthreads();
    // Hillis-Steele inclusive scan over 256
    for (int off = 1; off < 256; off <<= 1) {
        int t = (tid >= off) ? tsum[tid - off] : 0;
        __syncthreads();
        tsum[tid] += t;
        __syncthreads();
    }
    int excl = tsum[tid] - s4;   // exclusive offset of this thread within block
    int4 o;
    o.x = excl;
    o.y = excl + s1;
    o.z = excl + s2;
    o.w = excl + s3;
    *(int4*)(partial + base) = o;
    if (tid == 255) blocksums[blockIdx.x] = tsum[255];
}

// single block, 64 threads, scans 50 block sums (rest zero)
__global__ void k_scan_top(const int* __restrict__ blocksums, int* __restrict__ blockoffs) {
    __shared__ int s[64];
    int tid = threadIdx.x;
    int v = (tid < 50) ? blocksums[tid] : 0;
    s[tid] = v;
    __syncthreads();
    for (int off = 1; off < 64; off <<= 1) {
        int t = (tid >= off) ? s[tid - off] : 0;
        __syncthreads();
        s[tid] += t;
        __syncthreads();
    }
    if (tid < 50) blockoffs[tid] = s[tid] - v;  // exclusive
}

__global__ void k_rowptr(const int* __restrict__ partial, const int* __restrict__ blockoffs,
                         int* __restrict__ row_ptr) {
    int i = blockIdx.x * blockDim.x + threadIdx.x;
    if (i < N_NODES) row_ptr[i] = partial[i] + blockoffs[i >> 10];
    if (i == 0) row_ptr[N_NODES] = N_EDGES;
}

__global__ void k_fill(const int* __restrict__ src, const int* __restrict__ dst,
                       const int* __restrict__ row_ptr, int* __restrict__ cursor,
                       int* __restrict__ col) {
    int e = blockIdx.x * blockDim.x + threadIdx.x;
    if (e < N_EDGES) {
        int d = dst[e];
        int pos = row_ptr[d] + atomicAdd(&cursor[d], 1);
        col[pos] = src[e];
    }
}

// ---------------- aggregation: one wave per node ----------------

__global__ __launch_bounds__(256) void k_aggregate(const float* __restrict__ x,
                                                   const int* __restrict__ row_ptr,
                                                   const int* __restrict__ col,
                                                   float* __restrict__ agg) {
    int wave = threadIdx.x >> 6;
    int lane = threadIdx.x & 63;
    int node = blockIdx.x * 4 + wave;
    int beg = row_ptr[node];
    int end = row_ptr[node + 1];
    float2 acc = {0.f, 0.f};
    int f = lane * 2;
    for (int e = beg; e < end; ++e) {
        int s = col[e];
        float2 v = *(const float2*)(x + (size_t)s * HDIM + f);
        acc.x += v.x;
        acc.y += v.y;
    }
    *(float2*)(agg + (size_t)node * HDIM + f) = acc;
}

// ---------------- fused GEMM: y = relu([agg|x] @ [Wrel;Wroot] + b) ----------------
// tile: 64 rows x 128 cols, KB=32, 256 threads, 4x8 micro-tile per thread

#define BM 64
#define KB 32

__global__ __launch_bounds__(256) void k_gemm(const float* __restrict__ agg,
                                              const float* __restrict__ xin,
                                              const float* __restrict__ Wrel,
                                              const float* __restrict__ Wroot,
                                              const float* __restrict__ bias,
                                              float* __restrict__ y) {
    __shared__ float As[BM][KB + 1];   // stride 33: A reads are broadcast, conflict-free
    __shared__ float Bs[KB][HDIM];
    int tid = threadIdx.x;
    int m0 = blockIdx.x * BM;
    int col0 = (tid & 15) * 8;
    int row0 = (tid >> 4) * 4;

    float bb[8];
#pragma unroll
    for (int j = 0; j < 8; ++j) bb[j] = bias[col0 + j];

    float acc[4][8];
#pragma unroll
    for (int i = 0; i < 4; ++i)
#pragma unroll
        for (int j = 0; j < 8; ++j) acc[i][j] = 0.f;

    for (int kc = 0; kc < 8; ++kc) {
        int k0 = kc * KB;
        const float* Asrc = (k0 < HDIM) ? (agg + k0) : (xin + (k0 - HDIM));
        const float* Wsrc = (k0 < HDIM) ? (Wrel + (size_t)k0 * HDIM) : (Wroot + (size_t)(k0 - HDIM) * HDIM);

        // load A chunk: 64 rows x 32 k
        {
            int m = tid >> 2;     // 0..63
            int kq = tid & 3;     // 0..3
            const float* p = Asrc + (size_t)(m0 + m) * HDIM;
            float4 a0 = *(const float4*)(p + kq * 4);
            float4 a1 = *(const float4*)(p + (kq + 4) * 4);
            As[m][kq * 4 + 0] = a0.x; As[m][kq * 4 + 1] = a0.y;
            As[m][kq * 4 + 2] = a0.z; As[m][kq * 4 + 3] = a0.w;
            As[m][(kq + 4) * 4 + 0] = a1.x; As[m][(kq + 4) * 4 + 1] = a1.y;
            As[m][(kq + 4) * 4 + 2] = a1.z; As[m][(kq + 4) * 4 + 3] = a1.w;
        }
        // load B chunk: 32 k x 128 cols
        {
            int cq = tid & 31;    // 0..31
            int kk = tid >> 5;    // 0..7
#pragma unroll
            for (int r = 0; r < 4; ++r) {
                int k = kk + r * 8;
                float4 b = *(const float4*)(Wsrc + (size_t)k * HDIM + cq * 4);
                *(float4*)&Bs[k][cq * 4] = b;
            }
        }
        __syncthreads();

#pragma unroll
        for (int k = 0; k < KB; ++k) {
            float av[4];
#pragma unroll
            for (int i = 0; i < 4; ++i) av[i] = As[row0 + i][k];
            float bv[8];
            *(float4*)&bv[0] = *(const float4*)&Bs[k][col0];
            *(float4*)&bv[4] = *(const float4*)&Bs[k][col0 + 4];
#pragma unroll
            for (int i = 0; i < 4; ++i)
#pragma unroll
                for (int j = 0; j < 8; ++j) acc[i][j] += av[i] * bv[j];
        }
        __syncthreads();
    }

#pragma unroll
    for (int i = 0; i < 4; ++i) {
        int r = m0 + row0 + i;
        float o[8];
#pragma unroll
        for (int j = 0; j < 8; ++j) o[j] = fmaxf(acc[i][j] + bb[j], 0.f);
        *(float4*)(y + (size_t)r * HDIM + col0) = *(float4*)&o[0];
        *(float4*)(y + (size_t)r * HDIM + col0 + 4) = *(float4*)&o[4];
    }
}

// ---------------- mixup: xo = l*y + (1-l)*y[perm] ----------------

__global__ void k_mixup(const float* __restrict__ y, const int* __restrict__ perm,
                        const float* __restrict__ lam, float* __restrict__ xo) {
    int idx = blockIdx.x * blockDim.x + threadIdx.x;  // one float4 each
    int row = idx >> 5;        // 32 float4 per row
    int c4 = (idx & 31) * 4;
    float l = lam[0];
    float om = 1.f - l;
    int p = perm[row];
    float4 a = *(const float4*)(y + (size_t)row * HDIM + c4);
    float4 b = *(const float4*)(y + (size_t)p * HDIM + c4);
    float4 o;
    o.x = l * a.x + om * b.x;
    o.y = l * a.y + om * b.y;
    o.z = l * a.z + om * b.z;
    o.w = l * a.w + om * b.w;
    *(float4*)(xo + (size_t)row * HDIM + c4) = o;
}

// ---------------- pool + linear + log_softmax ----------------

__global__ __launch_bounds__(256) void k_pool(const float* __restrict__ x,
                                              const float* __restrict__ Wlin,
                                              const float* __restrict__ blin,
                                              float* __restrict__ out) {
    __shared__ float tmp[256];
    __shared__ float pooled[HDIM];
    __shared__ float logits[NOUT];
    __shared__ float lse_s;
    int g = blockIdx.x;
    int tid = threadIdx.x;
    int c = tid & 127;
    int half = tid >> 7;
    const float* base = x + (size_t)g * SEG * HDIM;
    float acc = 0.f;
    for (int r = half; r < SEG; r += 2) acc += base[(size_t)r * HDIM + c];
    tmp[tid] = acc;
    __syncthreads();
    if (half == 0) pooled[c] = tmp[c] + tmp[c + 128];
    __syncthreads();
    if (tid < NOUT) {
        float s = blin[tid];
        for (int k = 0; k < HDIM; ++k) s += pooled[k] * Wlin[k * NOUT + tid];
        logits[tid] = s;
    }
    __syncthreads();
    if (tid == 0) {
        float m = logits[0];
        for (int o = 1; o < NOUT; ++o) m = fmaxf(m, logits[o]);
        float se = 0.f;
        for (int o = 0; o < NOUT; ++o) se += expf(logits[o] - m);
        lse_s = m + logf(se);
    }
    __syncthreads();
    if (tid < NOUT) out[g * NOUT + tid] = logits[tid] - lse_s;
}

// ---------------- host ----------------

extern "C" void kernel_launch(void* const* d_in, const int* in_sizes, int n_in,
                              void* d_out, int out_size, void* d_ws, size_t ws_size,
                              hipStream_t stream) {
    const float* x0     = (const float*)d_in[0];
    const int*   edge   = (const int*)d_in[1];
    const int*   src    = edge;
    const int*   dst    = edge + N_EDGES;
    const float* lam    = (const float*)d_in[2];
    const int*   perm1  = (const int*)d_in[5];
    const int*   perm2  = (const int*)d_in[6];
    const int*   perm3  = (const int*)d_in[7];
    const float* W1_rel = (const float*)d_in[8];
    const float* b1_rel = (const float*)d_in[9];
    const float* W1_root= (const float*)d_in[10];
    const float* W2_rel = (const float*)d_in[11];
    const float* b2_rel = (const float*)d_in[12];
    const float* W2_root= (const float*)d_in[13];
    const float* W_lin  = (const float*)d_in[14];
    const float* b_lin  = (const float*)d_in[15];
    float* out = (float*)d_out;

    char* w = (char*)d_ws;
    size_t off = 0;
    auto alloc = [&](size_t bytes) -> void* {
        void* p = w + off;
        off = (off + bytes + 255) & ~(size_t)255;
        return p;
    };
    int* counts    = (int*)alloc((size_t)N_NODES * 4);
    int* cursor    = (int*)alloc((size_t)N_NODES * 4);
    int* partial   = (int*)alloc((size_t)N_NODES * 4);
    int* blocksums = (int*)alloc(64 * 4);
    int* blockoffs = (int*)alloc(64 * 4);
    int* row_ptr   = (int*)alloc((size_t)(N_NODES + 1) * 4);
    int* col       = (int*)alloc((size_t)N_EDGES * 4);
    float* agg  = (float*)alloc((size_t)N_NODES * HDIM * 4);
    float* ybuf = (float*)alloc((size_t)N_NODES * HDIM * 4);
    float* xA   = (float*)alloc((size_t)N_NODES * HDIM * 4);
    float* xB   = (float*)alloc((size_t)N_NODES * HDIM * 4);

    hipMemsetAsync(counts, 0, (size_t)N_NODES * 4, stream);
    hipMemsetAsync(cursor, 0, (size_t)N_NODES * 4, stream);

    // CSR build (edge_index constant across layers -> build once per call)
    k_count<<<N_EDGES / 256, 256, 0, stream>>>(dst, counts);
    k_scan_block<<<N_NODES / 1024, 256, 0, stream>>>(counts, partial, blocksums);
    k_scan_top<<<1, 64, 0, stream>>>(blocksums, blockoffs);
    k_rowptr<<<N_NODES / 256, 256, 0, stream>>>(partial, blockoffs, row_ptr);
    k_fill<<<N_EDGES / 256, 256, 0, stream>>>(src, dst, row_ptr, cursor, col);

    const int aggGrid = N_NODES / 4;
    const int gemmGrid = N_NODES / BM;
    const int mixGrid = (N_NODES * HDIM / 4) / 256;

    // layer 1
    k_aggregate<<<aggGrid, 256, 0, stream>>>(x0, row_ptr, col, agg);
    k_gemm<<<gemmGrid, 256, 0, stream>>>(agg, x0, W1_rel, W1_root, b1_rel, ybuf);
    k_mixup<<<mixGrid, 256, 0, stream>>>(ybuf, perm1, lam, xA);
    // layer 2
    k_aggregate<<<aggGrid, 256, 0, stream>>>(xA, row_ptr, col, agg);
    k_gemm<<<gemmGrid, 256, 0, stream>>>(agg, xA, W2_rel, W2_root, b2_rel, ybuf);
    k_mixup<<<mixGrid, 256, 0, stream>>>(ybuf, perm2, lam, xB);
    // layer 3 (reuses conv2 weights, per reference)
    k_aggregate<<<aggGrid, 256, 0, stream>>>(xB, row_ptr, col, agg);
    k_gemm<<<gemmGrid, 256, 0, stream>>>(agg, xB, W2_rel, W2_root, b2_rel, ybuf);
    k_mixup<<<mixGrid, 256, 0, stream>>>(ybuf, perm3, lam, xA);

    // pool + classifier + log_softmax
    k_pool<<<NGRAPH, 256, 0, stream>>>(xA, W_lin, b_lin, out);
}

// Round 2
// 574.526 us; speedup vs baseline: 1.2340x; 1.2340x over previous
//
#include <hip/hip_runtime.h>

#define N_NODES 51200
#define N_EDGES 819200
#define HDIM 128
#define NGRAPH 128
#define SEG 400
#define NOUT 10

typedef unsigned short ushort_t;

static __device__ __forceinline__ unsigned short f2bf(float f) {
    unsigned int u = __float_as_uint(f);
    unsigned int r = (u + 0x7fffu + ((u >> 16) & 1u)) >> 16;  // RNE
    return (unsigned short)r;
}
static __device__ __forceinline__ float bf2f(unsigned short h) {
    return __uint_as_float(((unsigned int)h) << 16);
}

// ---------------- CSR build ----------------

__global__ void k_count(const int* __restrict__ dst, int* __restrict__ counts) {
    int e = blockIdx.x * blockDim.x + threadIdx.x;
    if (e < N_EDGES) atomicAdd(&counts[dst[e]], 1);
}

__global__ void k_scan_block(const int* __restrict__ counts,
                             int* __restrict__ partial,
                             int* __restrict__ blocksums) {
    __shared__ int tsum[256];
    int tid = threadIdx.x;
    int base = blockIdx.x * 1024 + tid * 4;
    int4 c = *(const int4*)(counts + base);
    int s1 = c.x, s2 = s1 + c.y, s3 = s2 + c.z, s4 = s3 + c.w;
    tsum[tid] = s4;
    __syncthreads();
    for (int off = 1; off < 256; off <<= 1) {
        int t = (tid >= off) ? tsum[tid - off] : 0;
        __syncthreads();
        tsum[tid] += t;
        __syncthreads();
    }
    int excl = tsum[tid] - s4;
    int4 o;
    o.x = excl;
    o.y = excl + s1;
    o.z = excl + s2;
    o.w = excl + s3;
    *(int4*)(partial + base) = o;
    if (tid == 255) blocksums[blockIdx.x] = tsum[255];
}

__global__ void k_scan_top(const int* __restrict__ blocksums, int* __restrict__ blockoffs) {
    __shared__ int s[64];
    int tid = threadIdx.x;
    int v = (tid < 50) ? blocksums[tid] : 0;
    s[tid] = v;
    __syncthreads();
    for (int off = 1; off < 64; off <<= 1) {
        int t = (tid >= off) ? s[tid - off] : 0;
        __syncthreads();
        s[tid] += t;
        __syncthreads();
    }
    if (tid < 50) blockoffs[tid] = s[tid] - v;
}

__global__ void k_rowptr(const int* __restrict__ partial, const int* __restrict__ blockoffs,
                         int* __restrict__ row_ptr) {
    int i = blockIdx.x * blockDim.x + threadIdx.x;
    if (i < N_NODES) row_ptr[i] = partial[i] + blockoffs[i >> 10];
    if (i == 0) row_ptr[N_NODES] = N_EDGES;
}

__global__ void k_fill(const int* __restrict__ src, const int* __restrict__ dst,
                       const int* __restrict__ row_ptr, int* __restrict__ cursor,
                       int* __restrict__ col) {
    int e = blockIdx.x * blockDim.x + threadIdx.x;
    if (e < N_EDGES) {
        int d = dst[e];
        int pos = row_ptr[d] + atomicAdd(&cursor[d], 1);
        col[pos] = src[e];
    }
}

// ---------------- cast x0 -> bf16 ----------------

__global__ void k_cast(const float* __restrict__ x, ushort_t* __restrict__ xh) {
    int i = (blockIdx.x * 256 + threadIdx.x) * 4;
    float4 v = *(const float4*)(x + i);
    ushort4 h;
    h.x = f2bf(v.x); h.y = f2bf(v.y); h.z = f2bf(v.z); h.w = f2bf(v.w);
    *(ushort4*)(xh + i) = h;
}

// ---------------- aggregation: one wave per node, bf16 gather, unroll-8 ----------------

__global__ __launch_bounds__(256) void k_aggregate(const ushort_t* __restrict__ xh,
                                                   const int* __restrict__ row_ptr,
                                                   const int* __restrict__ col,
                                                   float* __restrict__ agg) {
    int wave = threadIdx.x >> 6;
    int lane = threadIdx.x & 63;
    int node = blockIdx.x * 4 + wave;
    int beg = row_ptr[node];
    int end = row_ptr[node + 1];
    size_t fo = (size_t)lane * 2;

    float ax[8], ay[8];
#pragma unroll
    for (int j = 0; j < 8; ++j) { ax[j] = 0.f; ay[j] = 0.f; }

    int e = beg;
    for (; e + 8 <= end; e += 8) {
        int c[8];
#pragma unroll
        for (int j = 0; j < 8; ++j) c[j] = col[e + j];   // wave-uniform -> scalar loads
#pragma unroll
        for (int j = 0; j < 8; ++j) {
            unsigned int v = *(const unsigned int*)(xh + (size_t)c[j] * HDIM + fo);
            ax[j] += __uint_as_float(v << 16);
            ay[j] += __uint_as_float(v & 0xffff0000u);
        }
    }
    for (; e < end; ++e) {
        int s = col[e];
        unsigned int v = *(const unsigned int*)(xh + (size_t)s * HDIM + fo);
        ax[0] += __uint_as_float(v << 16);
        ay[0] += __uint_as_float(v & 0xffff0000u);
    }

    float sx = (ax[0] + ax[1]) + (ax[2] + ax[3]) + ((ax[4] + ax[5]) + (ax[6] + ax[7]));
    float sy = (ay[0] + ay[1]) + (ay[2] + ay[3]) + ((ay[4] + ay[5]) + (ay[6] + ay[7]));
    float2 o; o.x = sx; o.y = sy;
    *(float2*)(agg + (size_t)node * HDIM + fo) = o;
}

// ---------------- fused GEMM: y = relu([agg(f32)|xh(bf16)] @ [Wrel;Wroot] + b) ----------

#define BM 64
#define KB 32

__global__ __launch_bounds__(256) void k_gemm(const float* __restrict__ agg,
                                              const ushort_t* __restrict__ xh,
                                              const float* __restrict__ Wrel,
                                              const float* __restrict__ Wroot,
                                              const float* __restrict__ bias,
                                              float* __restrict__ y) {
    __shared__ float As[BM][KB + 1];
    __shared__ float Bs[KB][HDIM];
    int tid = threadIdx.x;
    int m0 = blockIdx.x * BM;
    int col0 = (tid & 15) * 8;
    int row0 = (tid >> 4) * 4;

    float bb[8];
#pragma unroll
    for (int j = 0; j < 8; ++j) bb[j] = bias[col0 + j];

    float acc[4][8];
#pragma unroll
    for (int i = 0; i < 4; ++i)
#pragma unroll
        for (int j = 0; j < 8; ++j) acc[i][j] = 0.f;

    int am = tid >> 2;     // 0..63
    int akq = tid & 3;     // 0..3

    for (int kc = 0; kc < 8; ++kc) {
        int k0 = kc * KB;
        const float* Wsrc = (k0 < HDIM) ? (Wrel + (size_t)k0 * HDIM)
                                        : (Wroot + (size_t)(k0 - HDIM) * HDIM);
        // A chunk: 64 rows x 32 k
        if (k0 < HDIM) {
            const float* p = agg + (size_t)(m0 + am) * HDIM + k0;
            float4 a0 = *(const float4*)(p + akq * 4);
            float4 a1 = *(const float4*)(p + (akq + 4) * 4);
            As[am][akq * 4 + 0] = a0.x; As[am][akq * 4 + 1] = a0.y;
            As[am][akq * 4 + 2] = a0.z; As[am][akq * 4 + 3] = a0.w;
            As[am][(akq + 4) * 4 + 0] = a1.x; As[am][(akq + 4) * 4 + 1] = a1.y;
            As[am][(akq + 4) * 4 + 2] = a1.z; As[am][(akq + 4) * 4 + 3] = a1.w;
        } else {
            const ushort_t* p = xh + (size_t)(m0 + am) * HDIM + (k0 - HDIM);
            ushort4 h0 = *(const ushort4*)(p + akq * 4);
            ushort4 h1 = *(const ushort4*)(p + (akq + 4) * 4);
            As[am][akq * 4 + 0] = bf2f(h0.x); As[am][akq * 4 + 1] = bf2f(h0.y);
            As[am][akq * 4 + 2] = bf2f(h0.z); As[am][akq * 4 + 3] = bf2f(h0.w);
            As[am][(akq + 4) * 4 + 0] = bf2f(h1.x); As[am][(akq + 4) * 4 + 1] = bf2f(h1.y);
            As[am][(akq + 4) * 4 + 2] = bf2f(h1.z); As[am][(akq + 4) * 4 + 3] = bf2f(h1.w);
        }
        // B chunk: 32 k x 128 cols
        {
            int cq = tid & 31;
            int kk = tid >> 5;
#pragma unroll
            for (int r = 0; r < 4; ++r) {
                int k = kk + r * 8;
                float4 b = *(const float4*)(Wsrc + (size_t)k * HDIM + cq * 4);
                *(float4*)&Bs[k][cq * 4] = b;
            }
        }
        __syncthreads();

#pragma unroll
        for (int k = 0; k < KB; ++k) {
            float av[4];
#pragma unroll
            for (int i = 0; i < 4; ++i) av[i] = As[row0 + i][k];
            float bv[8];
            *(float4*)&bv[0] = *(const float4*)&Bs[k][col0];
            *(float4*)&bv[4] = *(const float4*)&Bs[k][col0 + 4];
#pragma unroll
            for (int i = 0; i < 4; ++i)
#pragma unroll
                for (int j = 0; j < 8; ++j) acc[i][j] += av[i] * bv[j];
        }
        __syncthreads();
    }

#pragma unroll
    for (int i = 0; i < 4; ++i) {
        int r = m0 + row0 + i;
        float o[8];
#pragma unroll
        for (int j = 0; j < 8; ++j) o[j] = fmaxf(acc[i][j] + bb[j], 0.f);
        *(float4*)(y + (size_t)r * HDIM + col0) = *(float4*)&o[0];
        *(float4*)(y + (size_t)r * HDIM + col0 + 4) = *(float4*)&o[4];
    }
}

// ---------------- mixup variants ----------------

__global__ void k_mixup_bf16(const float* __restrict__ y, const int* __restrict__ perm,
                             const float* __restrict__ lam, ushort_t* __restrict__ xo) {
    int idx = blockIdx.x * blockDim.x + threadIdx.x;
    int row = idx >> 5;
    int c4 = (idx & 31) * 4;
    float l = lam[0];
    float om = 1.f - l;
    int p = perm[row];
    float4 a = *(const float4*)(y + (size_t)row * HDIM + c4);
    float4 b = *(const float4*)(y + (size_t)p * HDIM + c4);
    ushort4 h;
    h.x = f2bf(l * a.x + om * b.x);
    h.y = f2bf(l * a.y + om * b.y);
    h.z = f2bf(l * a.z + om * b.z);
    h.w = f2bf(l * a.w + om * b.w);
    *(ushort4*)(xo + (size_t)row * HDIM + c4) = h;
}

__global__ void k_mixup_f32(const float* __restrict__ y, const int* __restrict__ perm,
                            const float* __restrict__ lam, float* __restrict__ xo) {
    int idx = blockIdx.x * blockDim.x + threadIdx.x;
    int row = idx >> 5;
    int c4 = (idx & 31) * 4;
    float l = lam[0];
    float om = 1.f - l;
    int p = perm[row];
    float4 a = *(const float4*)(y + (size_t)row * HDIM + c4);
    float4 b = *(const float4*)(y + (size_t)p * HDIM + c4);
    float4 o;
    o.x = l * a.x + om * b.x;
    o.y = l * a.y + om * b.y;
    o.z = l * a.z + om * b.z;
    o.w = l * a.w + om * b.w;
    *(float4*)(xo + (size_t)row * HDIM + c4) = o;
}

// ---------------- pool + linear + log_softmax ----------------

__global__ __launch_bounds__(256) void k_pool(const float* __restrict__ x,
                                              const float* __restrict__ Wlin,
                                              const float* __restrict__ blin,
                                              float* __restrict__ out) {
    __shared__ float tmp[256];
    __shared__ float pooled[HDIM];
    __shared__ float logits[NOUT];
    __shared__ float lse_s;
    int g = blockIdx.x;
    int tid = threadIdx.x;
    int c = tid & 127;
    int half = tid >> 7;
    const float* base = x + (size_t)g * SEG * HDIM;
    float acc = 0.f;
    for (int r = half; r < SEG; r += 2) acc += base[(size_t)r * HDIM + c];
    tmp[tid] = acc;
    __syncthreads();
    if (half == 0) pooled[c] = tmp[c] + tmp[c + 128];
    __syncthreads();
    if (tid < NOUT) {
        float s = blin[tid];
        for (int k = 0; k < HDIM; ++k) s += pooled[k] * Wlin[k * NOUT + tid];
        logits[tid] = s;
    }
    __syncthreads();
    if (tid == 0) {
        float m = logits[0];
        for (int o = 1; o < NOUT; ++o) m = fmaxf(m, logits[o]);
        float se = 0.f;
        for (int o = 0; o < NOUT; ++o) se += expf(logits[o] - m);
        lse_s = m + logf(se);
    }
    __syncthreads();
    if (tid < NOUT) out[g * NOUT + tid] = logits[tid] - lse_s;
}

// ---------------- host ----------------

extern "C" void kernel_launch(void* const* d_in, const int* in_sizes, int n_in,
                              void* d_out, int out_size, void* d_ws, size_t ws_size,
                              hipStream_t stream) {
    const float* x0     = (const float*)d_in[0];
    const int*   edge   = (const int*)d_in[1];
    const int*   src    = edge;
    const int*   dst    = edge + N_EDGES;
    const float* lam    = (const float*)d_in[2];
    const int*   perm1  = (const int*)d_in[5];
    const int*   perm2  = (const int*)d_in[6];
    const int*   perm3  = (const int*)d_in[7];
    const float* W1_rel = (const float*)d_in[8];
    const float* b1_rel = (const float*)d_in[9];
    const float* W1_root= (const float*)d_in[10];
    const float* W2_rel = (const float*)d_in[11];
    const float* b2_rel = (const float*)d_in[12];
    const float* W2_root= (const float*)d_in[13];
    const float* W_lin  = (const float*)d_in[14];
    const float* b_lin  = (const float*)d_in[15];
    float* out = (float*)d_out;

    char* w = (char*)d_ws;
    size_t off = 0;
    auto alloc = [&](size_t bytes) -> void* {
        void* p = w + off;
        off = (off + bytes + 255) & ~(size_t)255;
        return p;
    };
    int* counts    = (int*)alloc((size_t)N_NODES * 4);
    int* cursor    = (int*)alloc((size_t)N_NODES * 4);
    int* partial   = (int*)alloc((size_t)N_NODES * 4);
    int* blocksums = (int*)alloc(64 * 4);
    int* blockoffs = (int*)alloc(64 * 4);
    int* row_ptr   = (int*)alloc((size_t)(N_NODES + 1) * 4);
    int* col       = (int*)alloc((size_t)N_EDGES * 4);
    float*    agg  = (float*)alloc((size_t)N_NODES * HDIM * 4);   // also reused as f32 pool input
    float*    ybuf = (float*)alloc((size_t)N_NODES * HDIM * 4);
    ushort_t* xh   = (ushort_t*)alloc((size_t)N_NODES * HDIM * 2); // bf16 mirror, reused per layer

    hipMemsetAsync(counts, 0, (size_t)N_NODES * 4, stream);
    hipMemsetAsync(cursor, 0, (size_t)N_NODES * 4, stream);

    // CSR build (edge_index constant across layers -> build once per call)
    k_count<<<N_EDGES / 256, 256, 0, stream>>>(dst, counts);
    k_scan_block<<<N_NODES / 1024, 256, 0, stream>>>(counts, partial, blocksums);
    k_scan_top<<<1, 64, 0, stream>>>(blocksums, blockoffs);
    k_rowptr<<<N_NODES / 256, 256, 0, stream>>>(partial, blockoffs, row_ptr);
    k_fill<<<N_EDGES / 256, 256, 0, stream>>>(src, dst, row_ptr, cursor, col);

    const int aggGrid = N_NODES / 4;
    const int gemmGrid = N_NODES / BM;
    const int mixGrid = (N_NODES * HDIM / 4) / 256;

    k_cast<<<mixGrid, 256, 0, stream>>>(x0, xh);

    // layer 1
    k_aggregate<<<aggGrid, 256, 0, stream>>>(xh, row_ptr, col, agg);
    k_gemm<<<gemmGrid, 256, 0, stream>>>(agg, xh, W1_rel, W1_root, b1_rel, ybuf);
    k_mixup_bf16<<<mixGrid, 256, 0, stream>>>(ybuf, perm1, lam, xh);
    // layer 2
    k_aggregate<<<aggGrid, 256, 0, stream>>>(xh, row_ptr, col, agg);
    k_gemm<<<gemmGrid, 256, 0, stream>>>(agg, xh, W2_rel, W2_root, b2_rel, ybuf);
    k_mixup_bf16<<<mixGrid, 256, 0, stream>>>(ybuf, perm2, lam, xh);
    // layer 3 (reuses conv2 weights, per reference)
    k_aggregate<<<aggGrid, 256, 0, stream>>>(xh, row_ptr, col, agg);
    k_gemm<<<gemmGrid, 256, 0, stream>>>(agg, xh, W2_rel, W2_root, b2_rel, ybuf);
    k_mixup_f32<<<mixGrid, 256, 0, stream>>>(ybuf, perm3, lam, agg);  // agg reused as pool input

    // pool + classifier + log_softmax
    k_pool<<<NGRAPH, 256, 0, stream>>>(agg, W_lin, b_lin, out);
}

// Round 3
// 428.898 us; speedup vs baseline: 1.6529x; 1.3395x over previous
//
#include <hip/hip_runtime.h>

#define N_NODES 51200
#define N_EDGES 819200
#define HDIM 128
#define AK 256          // GEMM K = 2*HDIM (agg | x)
#define NGRAPH 128
#define SEG 400
#define NOUT 10

typedef unsigned short ushort_t;
typedef __attribute__((ext_vector_type(8))) short bf16x8;
typedef __attribute__((ext_vector_type(16))) float f32x16;

static __device__ __forceinline__ unsigned short f2bf(float f) {
    unsigned int u = __float_as_uint(f);
    unsigned int r = (u + 0x7fffu + ((u >> 16) & 1u)) >> 16;  // RNE
    return (unsigned short)r;
}
static __device__ __forceinline__ float bf2f(unsigned short h) {
    return __uint_as_float(((unsigned int)h) << 16);
}

// ---------------- CSR build ----------------

__global__ void k_count(const int* __restrict__ dst, int* __restrict__ counts) {
    int e = blockIdx.x * blockDim.x + threadIdx.x;
    if (e < N_EDGES) atomicAdd(&counts[dst[e]], 1);
}

__global__ void k_scan_block(const int* __restrict__ counts,
                             int* __restrict__ partial,
                             int* __restrict__ blocksums) {
    __shared__ int tsum[256];
    int tid = threadIdx.x;
    int base = blockIdx.x * 1024 + tid * 4;
    int4 c = *(const int4*)(counts + base);
    int s1 = c.x, s2 = s1 + c.y, s3 = s2 + c.z, s4 = s3 + c.w;
    tsum[tid] = s4;
    __syncthreads();
    for (int off = 1; off < 256; off <<= 1) {
        int t = (tid >= off) ? tsum[tid - off] : 0;
        __syncthreads();
        tsum[tid] += t;
        __syncthreads();
    }
    int excl = tsum[tid] - s4;
    int4 o;
    o.x = excl; o.y = excl + s1; o.z = excl + s2; o.w = excl + s3;
    *(int4*)(partial + base) = o;
    if (tid == 255) blocksums[blockIdx.x] = tsum[255];
}

__global__ void k_scan_top(const int* __restrict__ blocksums, int* __restrict__ blockoffs) {
    __shared__ int s[64];
    int tid = threadIdx.x;
    int v = (tid < 50) ? blocksums[tid] : 0;
    s[tid] = v;
    __syncthreads();
    for (int off = 1; off < 64; off <<= 1) {
        int t = (tid >= off) ? s[tid - off] : 0;
        __syncthreads();
        s[tid] += t;
        __syncthreads();
    }
    if (tid < 50) blockoffs[tid] = s[tid] - v;
}

__global__ void k_rowptr(const int* __restrict__ partial, const int* __restrict__ blockoffs,
                         int* __restrict__ row_ptr) {
    int i = blockIdx.x * blockDim.x + threadIdx.x;
    if (i < N_NODES) row_ptr[i] = partial[i] + blockoffs[i >> 10];
    if (i == 0) row_ptr[N_NODES] = N_EDGES;
}

__global__ void k_fill(const int* __restrict__ src, const int* __restrict__ dst,
                       const int* __restrict__ row_ptr, int* __restrict__ cursor,
                       int* __restrict__ col) {
    int e = blockIdx.x * blockDim.x + threadIdx.x;
    if (e < N_EDGES) {
        int d = dst[e];
        int pos = row_ptr[d] + atomicAdd(&cursor[d], 1);
        col[pos] = src[e];
    }
}

// ---------------- cast x0 -> Abuf right half (bf16) ----------------

__global__ void k_cast(const float* __restrict__ x, ushort_t* __restrict__ Abuf) {
    int idx = blockIdx.x * 256 + threadIdx.x;  // one float4 group
    int row = idx >> 5;
    int c4 = (idx & 31) * 4;
    float4 v = *(const float4*)(x + (size_t)row * HDIM + c4);
    ushort4 h;
    h.x = f2bf(v.x); h.y = f2bf(v.y); h.z = f2bf(v.z); h.w = f2bf(v.w);
    *(ushort4*)(Abuf + (size_t)row * AK + HDIM + c4) = h;
}

// ---------------- aggregation: wave/node, gather right half, write left half bf16 ----

__global__ __launch_bounds__(256) void k_aggregate(ushort_t* __restrict__ Abuf,
                                                   const int* __restrict__ row_ptr,
                                                   const int* __restrict__ col) {
    int wave = threadIdx.x >> 6;
    int lane = threadIdx.x & 63;
    int node = blockIdx.x * 4 + wave;
    int beg = row_ptr[node];
    int end = row_ptr[node + 1];
    size_t fo = (size_t)lane * 2;

    float ax[8], ay[8];
#pragma unroll
    for (int j = 0; j < 8; ++j) { ax[j] = 0.f; ay[j] = 0.f; }

    const ushort_t* xsrc = Abuf + HDIM;  // right half
    int e = beg;
    for (; e + 8 <= end; e += 8) {
        int c[8];
#pragma unroll
        for (int j = 0; j < 8; ++j) c[j] = col[e + j];   // wave-uniform -> scalar loads
#pragma unroll
        for (int j = 0; j < 8; ++j) {
            unsigned int v = *(const unsigned int*)(xsrc + (size_t)c[j] * AK + fo);
            ax[j] += __uint_as_float(v << 16);
            ay[j] += __uint_as_float(v & 0xffff0000u);
        }
    }
    for (; e < end; ++e) {
        unsigned int v = *(const unsigned int*)(xsrc + (size_t)col[e] * AK + fo);
        ax[0] += __uint_as_float(v << 16);
        ay[0] += __uint_as_float(v & 0xffff0000u);
    }

    float sx = (ax[0] + ax[1]) + (ax[2] + ax[3]) + ((ax[4] + ax[5]) + (ax[6] + ax[7]));
    float sy = (ay[0] + ay[1]) + (ay[2] + ay[3]) + ((ay[4] + ay[5]) + (ay[6] + ay[7]));
    unsigned int packed = (unsigned int)f2bf(sx) | ((unsigned int)f2bf(sy) << 16);
    *(unsigned int*)(Abuf + (size_t)node * AK + fo) = packed;
}

// ---------------- weight fragment prep: B[k][n] -> per-lane MFMA fragment order ----

__global__ void k_wfrag(const float* __restrict__ Wrel, const float* __restrict__ Wroot,
                        ushort_t* __restrict__ dstF) {
    int tid = blockIdx.x * 256 + threadIdx.x;  // 0..32767
    int j = tid & 7;
    int l = (tid >> 3) & 63;
    int s = (tid >> 9) & 15;
    int t = tid >> 13;
    int k = 16 * s + (l >> 5) * 8 + j;
    int n = 32 * t + (l & 31);
    float v = (k < HDIM) ? Wrel[(size_t)k * HDIM + n] : Wroot[(size_t)(k - HDIM) * HDIM + n];
    dstF[tid] = f2bf(v);
}

// ---------------- MFMA GEMM: y = relu([agg|x] @ W + b), bf16 in/out -------------
// one wave per 32 rows x 128 cols; no LDS, no barriers

__global__ __launch_bounds__(64) void k_gemm_mfma(const ushort_t* __restrict__ Abuf,
                                                  const ushort_t* __restrict__ Wfrag,
                                                  const float* __restrict__ bias,
                                                  ushort_t* __restrict__ y) {
    int lane = threadIdx.x;
    int row0 = blockIdx.x * 32;
    int m = lane & 31;
    int half = lane >> 5;

    f32x16 acc[4];
#pragma unroll
    for (int t = 0; t < 4; ++t) acc[t] = (f32x16)(0.f);

    float bb[4];
#pragma unroll
    for (int t = 0; t < 4; ++t) bb[t] = bias[t * 32 + m];

    const ushort_t* arow = Abuf + (size_t)(row0 + m) * AK + half * 8;
    const ushort_t* wf = Wfrag + (size_t)lane * 8;

#pragma unroll
    for (int s = 0; s < 16; ++s) {
        bf16x8 afrag = *(const bf16x8*)(arow + s * 16);
#pragma unroll
        for (int t = 0; t < 4; ++t) {
            bf16x8 bfrag = *(const bf16x8*)(wf + (size_t)(t * 16 + s) * 64 * 8);
            acc[t] = __builtin_amdgcn_mfma_f32_32x32x16_bf16(afrag, bfrag, acc[t], 0, 0, 0);
        }
    }

#pragma unroll
    for (int t = 0; t < 4; ++t) {
        int coln = t * 32 + m;
#pragma unroll
        for (int r = 0; r < 16; ++r) {
            int row = row0 + (r & 3) + 8 * (r >> 2) + 4 * half;
            float v = fmaxf(acc[t][r] + bb[t], 0.f);
            y[(size_t)row * HDIM + coln] = f2bf(v);
        }
    }
}

// ---------------- mixup: bf16 in -> bf16 out ----------------

__global__ void k_mixup_toA(const ushort_t* __restrict__ y, const int* __restrict__ perm,
                            const float* __restrict__ lam, ushort_t* __restrict__ Abuf) {
    int idx = blockIdx.x * 256 + threadIdx.x;
    int row = idx >> 5;
    int c4 = (idx & 31) * 4;
    float l = lam[0];
    float om = 1.f - l;
    int p = perm[row];
    ushort4 a = *(const ushort4*)(y + (size_t)row * HDIM + c4);
    ushort4 b = *(const ushort4*)(y + (size_t)p * HDIM + c4);
    ushort4 o;
    o.x = f2bf(l * bf2f(a.x) + om * bf2f(b.x));
    o.y = f2bf(l * bf2f(a.y) + om * bf2f(b.y));
    o.z = f2bf(l * bf2f(a.z) + om * bf2f(b.z));
    o.w = f2bf(l * bf2f(a.w) + om * bf2f(b.w));
    *(ushort4*)(Abuf + (size_t)row * AK + HDIM + c4) = o;
}

__global__ void k_mixup_fin(const ushort_t* __restrict__ y, const int* __restrict__ perm,
                            const float* __restrict__ lam, ushort_t* __restrict__ xfin) {
    int idx = blockIdx.x * 256 + threadIdx.x;
    int row = idx >> 5;
    int c4 = (idx & 31) * 4;
    float l = lam[0];
    float om = 1.f - l;
    int p = perm[row];
    ushort4 a = *(const ushort4*)(y + (size_t)row * HDIM + c4);
    ushort4 b = *(const ushort4*)(y + (size_t)p * HDIM + c4);
    ushort4 o;
    o.x = f2bf(l * bf2f(a.x) + om * bf2f(b.x));
    o.y = f2bf(l * bf2f(a.y) + om * bf2f(b.y));
    o.z = f2bf(l * bf2f(a.z) + om * bf2f(b.z));
    o.w = f2bf(l * bf2f(a.w) + om * bf2f(b.w));
    *(ushort4*)(xfin + (size_t)row * HDIM + c4) = o;
}

// ---------------- pool + linear + log_softmax (bf16 input, f32 math) ----------------

__global__ __launch_bounds__(256) void k_pool(const ushort_t* __restrict__ x,
                                              const float* __restrict__ Wlin,
                                              const float* __restrict__ blin,
                                              float* __restrict__ out) {
    __shared__ float tmp[256];
    __shared__ float pooled[HDIM];
    __shared__ float logits[NOUT];
    __shared__ float lse_s;
    int g = blockIdx.x;
    int tid = threadIdx.x;
    int c = tid & 127;
    int half = tid >> 7;
    const ushort_t* base = x + (size_t)g * SEG * HDIM;
    float acc = 0.f;
    for (int r = half; r < SEG; r += 2) acc += bf2f(base[(size_t)r * HDIM + c]);
    tmp[tid] = acc;
    __syncthreads();
    if (half == 0) pooled[c] = tmp[c] + tmp[c + 128];
    __syncthreads();
    if (tid < NOUT) {
        float s = blin[tid];
        for (int k = 0; k < HDIM; ++k) s += pooled[k] * Wlin[k * NOUT + tid];
        logits[tid] = s;
    }
    __syncthreads();
    if (tid == 0) {
        float m = logits[0];
        for (int o = 1; o < NOUT; ++o) m = fmaxf(m, logits[o]);
        float se = 0.f;
        for (int o = 0; o < NOUT; ++o) se += expf(logits[o] - m);
        lse_s = m + logf(se);
    }
    __syncthreads();
    if (tid < NOUT) out[g * NOUT + tid] = logits[tid] - lse_s;
}

// ---------------- host ----------------

extern "C" void kernel_launch(void* const* d_in, const int* in_sizes, int n_in,
                              void* d_out, int out_size, void* d_ws, size_t ws_size,
                              hipStream_t stream) {
    const float* x0     = (const float*)d_in[0];
    const int*   edge   = (const int*)d_in[1];
    const int*   src    = edge;
    const int*   dst    = edge + N_EDGES;
    const float* lam    = (const float*)d_in[2];
    const int*   perm1  = (const int*)d_in[5];
    const int*   perm2  = (const int*)d_in[6];
    const int*   perm3  = (const int*)d_in[7];
    const float* W1_rel = (const float*)d_in[8];
    const float* b1_rel = (const float*)d_in[9];
    const float* W1_root= (const float*)d_in[10];
    const float* W2_rel = (const float*)d_in[11];
    const float* b2_rel = (const float*)d_in[12];
    const float* W2_root= (const float*)d_in[13];
    const float* W_lin  = (const float*)d_in[14];
    const float* b_lin  = (const float*)d_in[15];
    float* out = (float*)d_out;

    char* w = (char*)d_ws;
    size_t off = 0;
    auto alloc = [&](size_t bytes) -> void* {
        void* p = w + off;
        off = (off + bytes + 255) & ~(size_t)255;
        return p;
    };
    int* counts    = (int*)alloc((size_t)N_NODES * 4);
    int* cursor    = (int*)alloc((size_t)N_NODES * 4);
    int* partial   = (int*)alloc((size_t)N_NODES * 4);
    int* blocksums = (int*)alloc(64 * 4);
    int* blockoffs = (int*)alloc(64 * 4);
    int* row_ptr   = (int*)alloc((size_t)(N_NODES + 1) * 4);
    int* col       = (int*)alloc((size_t)N_EDGES * 4);
    ushort_t* Abuf  = (ushort_t*)alloc((size_t)N_NODES * AK * 2);   // [N][256] bf16
    ushort_t* ybuf  = (ushort_t*)alloc((size_t)N_NODES * HDIM * 2); // [N][128] bf16
    ushort_t* xfin  = (ushort_t*)alloc((size_t)N_NODES * HDIM * 2); // layer-3 out
    ushort_t* Wfrag1 = (ushort_t*)alloc(32768 * 2);
    ushort_t* Wfrag2 = (ushort_t*)alloc(32768 * 2);

    hipMemsetAsync(counts, 0, (size_t)N_NODES * 4, stream);
    hipMemsetAsync(cursor, 0, (size_t)N_NODES * 4, stream);

    // CSR build (edge_index constant across layers -> build once per call)
    k_count<<<N_EDGES / 256, 256, 0, stream>>>(dst, counts);
    k_scan_block<<<N_NODES / 1024, 256, 0, stream>>>(counts, partial, blocksums);
    k_scan_top<<<1, 64, 0, stream>>>(blocksums, blockoffs);
    k_rowptr<<<N_NODES / 256, 256, 0, stream>>>(partial, blockoffs, row_ptr);
    k_fill<<<N_EDGES / 256, 256, 0, stream>>>(src, dst, row_ptr, cursor, col);

    // weight fragments
    k_wfrag<<<128, 256, 0, stream>>>(W1_rel, W1_root, Wfrag1);
    k_wfrag<<<128, 256, 0, stream>>>(W2_rel, W2_root, Wfrag2);

    const int aggGrid  = N_NODES / 4;
    const int gemmGrid = N_NODES / 32;
    const int elGrid   = (N_NODES * HDIM / 4) / 256;

    k_cast<<<elGrid, 256, 0, stream>>>(x0, Abuf);

    // layer 1
    k_aggregate<<<aggGrid, 256, 0, stream>>>(Abuf, row_ptr, col);
    k_gemm_mfma<<<gemmGrid, 64, 0, stream>>>(Abuf, Wfrag1, b1_rel, ybuf);
    k_mixup_toA<<<elGrid, 256, 0, stream>>>(ybuf, perm1, lam, Abuf);
    // layer 2
    k_aggregate<<<aggGrid, 256, 0, stream>>>(Abuf, row_ptr, col);
    k_gemm_mfma<<<gemmGrid, 64, 0, stream>>>(Abuf, Wfrag2, b2_rel, ybuf);
    k_mixup_toA<<<elGrid, 256, 0, stream>>>(ybuf, perm2, lam, Abuf);
    // layer 3 (reuses conv2 weights, per reference)
    k_aggregate<<<aggGrid, 256, 0, stream>>>(Abuf, row_ptr, col);
    k_gemm_mfma<<<gemmGrid, 64, 0, stream>>>(Abuf, Wfrag2, b2_rel, ybuf);
    k_mixup_fin<<<elGrid, 256, 0, stream>>>(ybuf, perm3, lam, xfin);

    // pool + classifier + log_softmax
    k_pool<<<NGRAPH, 256, 0, stream>>>(xfin, W_lin, b_lin, out);
}

// Round 4
// 387.299 us; speedup vs baseline: 1.8305x; 1.1074x over previous
//
#include <hip/hip_runtime.h>

#define N_NODES 51200
#define N_EDGES 819200
#define HDIM 128
#define AK 256          // GEMM K = 2*HDIM (agg | x)
#define NGRAPH 128
#define SEG 400
#define NOUT 10

typedef unsigned short ushort_t;
typedef __attribute__((ext_vector_type(8))) short bf16x8;
typedef __attribute__((ext_vector_type(16))) float f32x16;

static __device__ __forceinline__ unsigned short f2bf(float f) {
    unsigned int u = __float_as_uint(f);
    unsigned int r = (u + 0x7fffu + ((u >> 16) & 1u)) >> 16;  // RNE
    return (unsigned short)r;
}
static __device__ __forceinline__ float bf2f(unsigned short h) {
    return __uint_as_float(((unsigned int)h) << 16);
}

// ---------------- CSR build ----------------

__global__ void k_count(const int* __restrict__ dst, int* __restrict__ counts) {
    int e = blockIdx.x * blockDim.x + threadIdx.x;
    if (e < N_EDGES) atomicAdd(&counts[dst[e]], 1);
}

__global__ void k_scan_block(const int* __restrict__ counts,
                             int* __restrict__ partial,
                             int* __restrict__ blocksums) {
    __shared__ int tsum[256];
    int tid = threadIdx.x;
    int base = blockIdx.x * 1024 + tid * 4;
    int4 c = *(const int4*)(counts + base);
    int s1 = c.x, s2 = s1 + c.y, s3 = s2 + c.z, s4 = s3 + c.w;
    tsum[tid] = s4;
    __syncthreads();
    for (int off = 1; off < 256; off <<= 1) {
        int t = (tid >= off) ? tsum[tid - off] : 0;
        __syncthreads();
        tsum[tid] += t;
        __syncthreads();
    }
    int excl = tsum[tid] - s4;
    int4 o;
    o.x = excl; o.y = excl + s1; o.z = excl + s2; o.w = excl + s3;
    *(int4*)(partial + base) = o;
    if (tid == 255) blocksums[blockIdx.x] = tsum[255];
}

__global__ void k_scan_top(const int* __restrict__ blocksums, int* __restrict__ blockoffs) {
    __shared__ int s[64];
    int tid = threadIdx.x;
    int v = (tid < 50) ? blocksums[tid] : 0;
    s[tid] = v;
    __syncthreads();
    for (int off = 1; off < 64; off <<= 1) {
        int t = (tid >= off) ? s[tid - off] : 0;
        __syncthreads();
        s[tid] += t;
        __syncthreads();
    }
    if (tid < 50) blockoffs[tid] = s[tid] - v;
}

__global__ void k_rowptr(const int* __restrict__ partial, const int* __restrict__ blockoffs,
                         int* __restrict__ row_ptr) {
    int i = blockIdx.x * blockDim.x + threadIdx.x;
    if (i < N_NODES) row_ptr[i] = partial[i] + blockoffs[i >> 10];
    if (i == 0) row_ptr[N_NODES] = N_EDGES;
}

__global__ void k_fill(const int* __restrict__ src, const int* __restrict__ dst,
                       const int* __restrict__ row_ptr, int* __restrict__ cursor,
                       int* __restrict__ col) {
    int e = blockIdx.x * blockDim.x + threadIdx.x;
    if (e < N_EDGES) {
        int d = dst[e];
        int pos = row_ptr[d] + atomicAdd(&cursor[d], 1);
        col[pos] = src[e];
    }
}

// ---------------- cast x0 -> Abuf right half (bf16) ----------------

__global__ void k_cast(const float* __restrict__ x, ushort_t* __restrict__ Abuf) {
    int idx = blockIdx.x * 256 + threadIdx.x;
    int row = idx >> 5;
    int c4 = (idx & 31) * 4;
    float4 v = *(const float4*)(x + (size_t)row * HDIM + c4);
    ushort4 h;
    h.x = f2bf(v.x); h.y = f2bf(v.y); h.z = f2bf(v.z); h.w = f2bf(v.w);
    *(ushort4*)(Abuf + (size_t)row * AK + HDIM + c4) = h;
}

// ---------------- aggregation: wave/node, gather right half, write left half bf16 ----

__global__ __launch_bounds__(256) void k_aggregate(ushort_t* __restrict__ Abuf,
                                                   const int* __restrict__ row_ptr,
                                                   const int* __restrict__ col) {
    int wave = threadIdx.x >> 6;
    int lane = threadIdx.x & 63;
    int node = blockIdx.x * 4 + wave;
    int beg = row_ptr[node];
    int end = row_ptr[node + 1];
    size_t fo = (size_t)lane * 2;

    float ax[8], ay[8];
#pragma unroll
    for (int j = 0; j < 8; ++j) { ax[j] = 0.f; ay[j] = 0.f; }

    const ushort_t* xsrc = Abuf + HDIM;
    int e = beg;
    for (; e + 8 <= end; e += 8) {
        int c[8];
#pragma unroll
        for (int j = 0; j < 8; ++j) c[j] = col[e + j];
#pragma unroll
        for (int j = 0; j < 8; ++j) {
            unsigned int v = *(const unsigned int*)(xsrc + (size_t)c[j] * AK + fo);
            ax[j] += __uint_as_float(v << 16);
            ay[j] += __uint_as_float(v & 0xffff0000u);
        }
    }
    for (; e < end; ++e) {
        unsigned int v = *(const unsigned int*)(xsrc + (size_t)col[e] * AK + fo);
        ax[0] += __uint_as_float(v << 16);
        ay[0] += __uint_as_float(v & 0xffff0000u);
    }

    float sx = (ax[0] + ax[1]) + (ax[2] + ax[3]) + ((ax[4] + ax[5]) + (ax[6] + ax[7]));
    float sy = (ay[0] + ay[1]) + (ay[2] + ay[3]) + ((ay[4] + ay[5]) + (ay[6] + ay[7]));
    unsigned int packed = (unsigned int)f2bf(sx) | ((unsigned int)f2bf(sy) << 16);
    *(unsigned int*)(Abuf + (size_t)node * AK + fo) = packed;
}

// ---------------- weight fragment prep ----------------

__global__ void k_wfrag(const float* __restrict__ Wrel, const float* __restrict__ Wroot,
                        ushort_t* __restrict__ dstF) {
    int tid = blockIdx.x * 256 + threadIdx.x;  // 0..32767
    int j = tid & 7;
    int l = (tid >> 3) & 63;
    int s = (tid >> 9) & 15;
    int t = tid >> 13;
    int k = 16 * s + (l >> 5) * 8 + j;
    int n = 32 * t + (l & 31);
    float v = (k < HDIM) ? Wrel[(size_t)k * HDIM + n] : Wroot[(size_t)(k - HDIM) * HDIM + n];
    dstF[tid] = f2bf(v);
}

// ---------------- MFMA GEMM (layers 1-2): y = relu([agg|x] @ W + b) -------------
// one wave per 32 rows x 128 cols; LDS transpose for coalesced 16B stores

__global__ __launch_bounds__(64) void k_gemm_mfma(const ushort_t* __restrict__ Abuf,
                                                  const ushort_t* __restrict__ Wfrag,
                                                  const float* __restrict__ bias,
                                                  ushort_t* __restrict__ y) {
    __shared__ ushort_t sm[32][136];   // stride 136 ushorts = 272 B (16B-aligned rows)
    int lane = threadIdx.x;
    int row0 = blockIdx.x * 32;
    int m = lane & 31;
    int half = lane >> 5;

    f32x16 acc[4];
#pragma unroll
    for (int t = 0; t < 4; ++t) acc[t] = (f32x16)(0.f);

    float bb[4];
#pragma unroll
    for (int t = 0; t < 4; ++t) bb[t] = bias[t * 32 + m];

    const ushort_t* arow = Abuf + (size_t)(row0 + m) * AK + half * 8;
    const ushort_t* wf = Wfrag + (size_t)lane * 8;

#pragma unroll
    for (int s = 0; s < 16; ++s) {
        bf16x8 afrag = *(const bf16x8*)(arow + s * 16);
#pragma unroll
        for (int t = 0; t < 4; ++t) {
            bf16x8 bfrag = *(const bf16x8*)(wf + (size_t)(t * 16 + s) * 64 * 8);
            acc[t] = __builtin_amdgcn_mfma_f32_32x32x16_bf16(afrag, bfrag, acc[t], 0, 0, 0);
        }
    }

    // epilogue: bias+relu -> LDS (bf16) -> coalesced 16B stores
#pragma unroll
    for (int t = 0; t < 4; ++t) {
#pragma unroll
        for (int r = 0; r < 16; ++r) {
            int rowL = (r & 3) + 8 * (r >> 2) + 4 * half;
            sm[rowL][t * 32 + m] = f2bf(fmaxf(acc[t][r] + bb[t], 0.f));
        }
    }
    __syncthreads();  // single wave: cheap; guarantees LDS visibility
    int seg = lane & 15;
    int rbase = lane >> 4;
#pragma unroll
    for (int it = 0; it < 8; ++it) {
        int rowL = rbase + it * 4;
        int4 chunk = *(const int4*)&sm[rowL][seg * 8];
        *(int4*)(y + (size_t)(row0 + rowL) * HDIM + seg * 8) = chunk;
    }
}

// ---------------- MFMA GEMM layer-3: relu -> per-graph pooled atomicAdd ----------
// final mixup is a pooling no-op (perm3 permutes within segments)

__global__ __launch_bounds__(64) void k_gemm_pool(const ushort_t* __restrict__ Abuf,
                                                  const ushort_t* __restrict__ Wfrag,
                                                  const float* __restrict__ bias,
                                                  float* __restrict__ pooled) {
    int lane = threadIdx.x;
    int row0 = blockIdx.x * 32;
    int m = lane & 31;
    int half = lane >> 5;

    f32x16 acc[4];
#pragma unroll
    for (int t = 0; t < 4; ++t) acc[t] = (f32x16)(0.f);

    float bb[4];
#pragma unroll
    for (int t = 0; t < 4; ++t) bb[t] = bias[t * 32 + m];

    const ushort_t* arow = Abuf + (size_t)(row0 + m) * AK + half * 8;
    const ushort_t* wf = Wfrag + (size_t)lane * 8;

#pragma unroll
    for (int s = 0; s < 16; ++s) {
        bf16x8 afrag = *(const bf16x8*)(arow + s * 16);
#pragma unroll
        for (int t = 0; t < 4; ++t) {
            bf16x8 bfrag = *(const bf16x8*)(wf + (size_t)(t * 16 + s) * 64 * 8);
            acc[t] = __builtin_amdgcn_mfma_f32_32x32x16_bf16(afrag, bfrag, acc[t], 0, 0, 0);
        }
    }

    int g0 = row0 / SEG;
    int bnd = (g0 + 1) * SEG;          // first row of next graph
    int straddle = (row0 + 31 >= bnd);

#pragma unroll
    for (int t = 0; t < 4; ++t) {
        float s0 = 0.f, s1 = 0.f;
#pragma unroll
        for (int r = 0; r < 16; ++r) {
            int row = row0 + (r & 3) + 8 * (r >> 2) + 4 * half;
            float v = fmaxf(acc[t][r] + bb[t], 0.f);
            if (row < bnd) s0 += v; else s1 += v;
        }
        s0 += __shfl_xor(s0, 32);
        s1 += __shfl_xor(s1, 32);
        if (half == 0) {
            atomicAdd(&pooled[g0 * HDIM + t * 32 + m], s0);
            if (straddle) atomicAdd(&pooled[(g0 + 1) * HDIM + t * 32 + m], s1);
        }
    }
}

// ---------------- mixup: bf16 y -> Abuf right half ----------------

__global__ void k_mixup_toA(const ushort_t* __restrict__ y, const int* __restrict__ perm,
                            const float* __restrict__ lam, ushort_t* __restrict__ Abuf) {
    int idx = blockIdx.x * 256 + threadIdx.x;
    int row = idx >> 5;
    int c4 = (idx & 31) * 4;
    float l = lam[0];
    float om = 1.f - l;
    int p = perm[row];
    ushort4 a = *(const ushort4*)(y + (size_t)row * HDIM + c4);
    ushort4 b = *(const ushort4*)(y + (size_t)p * HDIM + c4);
    ushort4 o;
    o.x = f2bf(l * bf2f(a.x) + om * bf2f(b.x));
    o.y = f2bf(l * bf2f(a.y) + om * bf2f(b.y));
    o.z = f2bf(l * bf2f(a.z) + om * bf2f(b.z));
    o.w = f2bf(l * bf2f(a.w) + om * bf2f(b.w));
    *(ushort4*)(Abuf + (size_t)row * AK + HDIM + c4) = o;
}

// ---------------- final: linear + log_softmax from pooled ----------------

__global__ __launch_bounds__(64) void k_final(const float* __restrict__ pooled,
                                              const float* __restrict__ Wlin,
                                              const float* __restrict__ blin,
                                              float* __restrict__ out) {
    int g = blockIdx.x;
    int lane = threadIdx.x;
    float2 v = *(const float2*)(pooled + (size_t)g * HDIM + lane * 2);
    float p[NOUT];
#pragma unroll
    for (int o = 0; o < NOUT; ++o)
        p[o] = v.x * Wlin[(size_t)(2 * lane) * NOUT + o] +
               v.y * Wlin[(size_t)(2 * lane + 1) * NOUT + o];
#pragma unroll
    for (int mask = 1; mask < 64; mask <<= 1)
#pragma unroll
        for (int o = 0; o < NOUT; ++o) p[o] += __shfl_xor(p[o], mask);
    if (lane == 0) {
        float lg[NOUT];
        float mx = -1e30f;
#pragma unroll
        for (int o = 0; o < NOUT; ++o) { lg[o] = p[o] + blin[o]; mx = fmaxf(mx, lg[o]); }
        float se = 0.f;
#pragma unroll
        for (int o = 0; o < NOUT; ++o) se += expf(lg[o] - mx);
        float lse = mx + logf(se);
#pragma unroll
        for (int o = 0; o < NOUT; ++o) out[g * NOUT + o] = lg[o] - lse;
    }
}

// ---------------- host ----------------

extern "C" void kernel_launch(void* const* d_in, const int* in_sizes, int n_in,
                              void* d_out, int out_size, void* d_ws, size_t ws_size,
                              hipStream_t stream) {
    const float* x0     = (const float*)d_in[0];
    const int*   edge   = (const int*)d_in[1];
    const int*   src    = edge;
    const int*   dst    = edge + N_EDGES;
    const float* lam    = (const float*)d_in[2];
    const int*   perm1  = (const int*)d_in[5];
    const int*   perm2  = (const int*)d_in[6];
    const float* W1_rel = (const float*)d_in[8];
    const float* b1_rel = (const float*)d_in[9];
    const float* W1_root= (const float*)d_in[10];
    const float* W2_rel = (const float*)d_in[11];
    const float* b2_rel = (const float*)d_in[12];
    const float* W2_root= (const float*)d_in[13];
    const float* W_lin  = (const float*)d_in[14];
    const float* b_lin  = (const float*)d_in[15];
    float* out = (float*)d_out;

    char* w = (char*)d_ws;
    size_t off = 0;
    auto alloc = [&](size_t bytes) -> void* {
        void* p = w + off;
        off = (off + bytes + 255) & ~(size_t)255;
        return p;
    };
    int* counts    = (int*)alloc((size_t)N_NODES * 4);
    int* cursor    = (int*)alloc((size_t)N_NODES * 4);
    int* partial   = (int*)alloc((size_t)N_NODES * 4);
    int* blocksums = (int*)alloc(64 * 4);
    int* blockoffs = (int*)alloc(64 * 4);
    int* row_ptr   = (int*)alloc((size_t)(N_NODES + 1) * 4);
    int* col       = (int*)alloc((size_t)N_EDGES * 4);
    ushort_t* Abuf   = (ushort_t*)alloc((size_t)N_NODES * AK * 2);   // [N][256] bf16
    ushort_t* ybuf   = (ushort_t*)alloc((size_t)N_NODES * HDIM * 2); // [N][128] bf16
    ushort_t* Wfrag1 = (ushort_t*)alloc(32768 * 2);
    ushort_t* Wfrag2 = (ushort_t*)alloc(32768 * 2);
    float* pooled    = (float*)alloc((size_t)NGRAPH * HDIM * 4);

    hipMemsetAsync(counts, 0, (size_t)N_NODES * 4, stream);
    hipMemsetAsync(cursor, 0, (size_t)N_NODES * 4, stream);
    hipMemsetAsync(pooled, 0, (size_t)NGRAPH * HDIM * 4, stream);

    // CSR build
    k_count<<<N_EDGES / 256, 256, 0, stream>>>(dst, counts);
    k_scan_block<<<N_NODES / 1024, 256, 0, stream>>>(counts, partial, blocksums);
    k_scan_top<<<1, 64, 0, stream>>>(blocksums, blockoffs);
    k_rowptr<<<N_NODES / 256, 256, 0, stream>>>(partial, blockoffs, row_ptr);
    k_fill<<<N_EDGES / 256, 256, 0, stream>>>(src, dst, row_ptr, cursor, col);

    // weight fragments
    k_wfrag<<<128, 256, 0, stream>>>(W1_rel, W1_root, Wfrag1);
    k_wfrag<<<128, 256, 0, stream>>>(W2_rel, W2_root, Wfrag2);

    const int aggGrid  = N_NODES / 4;
    const int gemmGrid = N_NODES / 32;
    const int elGrid   = (N_NODES * HDIM / 4) / 256;

    k_cast<<<elGrid, 256, 0, stream>>>(x0, Abuf);

    // layer 1
    k_aggregate<<<aggGrid, 256, 0, stream>>>(Abuf, row_ptr, col);
    k_gemm_mfma<<<gemmGrid, 64, 0, stream>>>(Abuf, Wfrag1, b1_rel, ybuf);
    k_mixup_toA<<<elGrid, 256, 0, stream>>>(ybuf, perm1, lam, Abuf);
    // layer 2
    k_aggregate<<<aggGrid, 256, 0, stream>>>(Abuf, row_ptr, col);
    k_gemm_mfma<<<gemmGrid, 64, 0, stream>>>(Abuf, Wfrag2, b2_rel, ybuf);
    k_mixup_toA<<<elGrid, 256, 0, stream>>>(ybuf, perm2, lam, Abuf);
    // layer 3 (reuses conv2 weights; mixup3 is a pooling no-op -> fused pool)
    k_aggregate<<<aggGrid, 256, 0, stream>>>(Abuf, row_ptr, col);
    k_gemm_pool<<<gemmGrid, 64, 0, stream>>>(Abuf, Wfrag2, b2_rel, pooled);

    // classifier + log_softmax
    k_final<<<NGRAPH, 64, 0, stream>>>(pooled, W_lin, b_lin, out);
}